// Round 1
// baseline (362.699 us; speedup 1.0000x reference)
//
#include <hip/hip_runtime.h>
#include <math.h>

// Problem constants
#define IMGS 256
#define NANG 50
#define BATCH 4
#define NCNN 32
#define PIX (IMGS*IMGS)              // 65536
#define NPIX (BATCH*PIX)             // 262144
#define SINO (BATCH*NANG*IMGS)       // 51200

// Workspace layout (floats)
#define OFF_COS   0
#define OFF_SIN   64
#define OFF_TAPS  128        // 511 taps (+1 pad)
#define OFF_MIMG  640        // 262144  masked image
#define OFF_PART  262784     // 8*51200 partial forward sums
#define OFF_FILT  672384     // 51200   filtered sinogram
#define OFF_YUPD  723584     // 262144  y_img_update
#define OFF_H1    985728     // 4*32*65536
#define OFF_H2    9374336    // 4*32*65536
// total 17762944 floats = ~71 MB

static constexpr double PI_D = 3.14159265358979323846;

// ---------------- K0: trig + ramp-filter taps ----------------
// filter_sinogram == circular conv (P=512) of zero-padded row with g=irfft(ramp),
// ramp[k]=2k/512. Signal support [0,256) + out range [0,256) => plain 511-tap conv.
__global__ void k_precompute(const float* __restrict__ angles, float* __restrict__ ws) {
    int tid = threadIdx.x;
    if (tid < NANG) {
        float a = angles[tid];
        ws[OFF_COS + tid] = cosf(a);
        ws[OFF_SIN + tid] = sinf(a);
    }
    if (tid < 511) {
        int d = tid - 255;
        int n = d < 0 ? d + 512 : d;
        // irfft: g[n] = (1/512)[X256*cos(pi n) + 2*sum_{k=1}^{255} (k/256) cos(2pi k n/512)]
        double sum = (d & 1) ? -1.0 : 1.0;   // X256 = 1.0
        for (int k = 1; k <= 255; ++k) {
            int m = (k * n) & 511;           // exact arg reduction
            sum += 2.0 * ((double)k / 256.0) * cos(2.0 * PI_D * (double)m / 512.0);
        }
        ws[OFF_TAPS + tid] = (float)(sum / 512.0 * PI_D / 100.0); // fold pi/(2A), A=50
    }
}

// ---------------- K0b: mask image (img * circle_mask) ----------------
__global__ void k_mask_img(const float* __restrict__ yprev, float* __restrict__ ws) {
    int p = blockIdx.x * 256 + threadIdx.x;
    int i = (p >> 8) & 255, j = p & 255;
    float di = (float)i - 127.5f, dj = (float)j - 127.5f;
    float m = (di * di + dj * dj <= 16384.0f) ? 1.0f : 0.0f;
    ws[OFF_MIMG + p] = yprev[p] * m;
}

__device__ __forceinline__ float ldpix(const float* __restrict__ im, int i, int j) {
    return ((unsigned)i < 256u && (unsigned)j < 256u) ? im[i * 256 + j] : 0.0f;
}

// ---------------- K1: forward radon, 8-way split over t ----------------
__global__ void k_radon_fwd(float* __restrict__ ws) {
    const float* __restrict__ mimg = ws + OFF_MIMG;
    int bi  = blockIdx.x;
    int seg = bi & 7;
    int ra  = bi >> 3;            // b*50 + a
    int a   = ra % NANG;
    int b   = ra / NANG;
    float cs = ws[OFF_COS + a], sn = ws[OFF_SIN + a];
    int s = threadIdx.x;
    float sc = (float)s - 127.5f;
    const float* __restrict__ im = mimg + b * PIX;
    float acc = 0.0f;
    int t0 = seg * 32;
    for (int t = t0; t < t0 + 32; ++t) {
        float tc  = (float)t - 127.5f;
        float col = (sc * cs - tc * sn) + 127.5f;   // x + c
        float row = (sc * sn + tc * cs) + 127.5f;   // y + c
        float fr = floorf(row), fc = floorf(col);
        int   i0 = (int)fr,     j0 = (int)fc;
        float wr = row - fr,    wc = col - fc;
        float v00 = ldpix(im, i0,     j0);
        float v01 = ldpix(im, i0,     j0 + 1);
        float v10 = ldpix(im, i0 + 1, j0);
        float v11 = ldpix(im, i0 + 1, j0 + 1);
        acc += v00 * (1.0f - wr) * (1.0f - wc) + v01 * (1.0f - wr) * wc
             + v10 * wr * (1.0f - wc)          + v11 * wr * wc;
    }
    ws[OFF_PART + (seg * 200 + ra) * 256 + s] = acc;
}

// ---------------- K2: reduce partials, subtract sino, 511-tap filter ----------------
__global__ void k_filter(const float* __restrict__ xsino, float* __restrict__ ws) {
    __shared__ float srow[256];
    __shared__ float staps[512];
    int r = blockIdx.x, tid = threadIdx.x;
    float v = -xsino[r * 256 + tid];
    #pragma unroll
    for (int seg = 0; seg < 8; ++seg) v += ws[OFF_PART + (seg * 200 + r) * 256 + tid];
    srow[tid] = v;
    staps[tid] = ws[OFF_TAPS + tid];
    if (tid < 255) staps[256 + tid] = ws[OFF_TAPS + 256 + tid];
    __syncthreads();
    float acc = 0.0f;
    #pragma unroll 8
    for (int m = 0; m < 256; ++m) acc += srow[m] * staps[tid - m + 255];
    ws[OFF_FILT + r * 256 + tid] = acc;
}

// ---------------- K3: backprojection + y_img_update ----------------
__global__ void k_backproj(const float* __restrict__ yprev, const float* __restrict__ stepp,
                           float* __restrict__ ws, float* __restrict__ dout) {
    __shared__ float sf[NANG * 256];   // 50 KB: whole filtered sinogram of this batch
    __shared__ float scs[NANG], ssn[NANG];
    int b = blockIdx.x >> 8, i = blockIdx.x & 255, j = threadIdx.x;
    for (int idx = threadIdx.x; idx < NANG * 256; idx += 256)
        sf[idx] = ws[OFF_FILT + b * (NANG * 256) + idx];
    if (threadIdx.x < NANG) {
        scs[threadIdx.x] = ws[OFF_COS + threadIdx.x];
        ssn[threadIdx.x] = ws[OFF_SIN + threadIdx.x];
    }
    __syncthreads();
    float yy = (float)i - 127.5f, xx = (float)j - 127.5f;
    float acc = 0.0f;
    #pragma unroll 5
    for (int a = 0; a < NANG; ++a) {
        float idxf = xx * scs[a] + yy * ssn[a] + 127.5f;
        float fl = floorf(idxf);
        int i0 = (int)fl;
        i0 = min(max(i0, 0), 254);
        float w = idxf - (float)i0;
        float v = sf[a * 256 + i0] * (1.0f - w) + sf[a * 256 + i0 + 1] * w;
        acc += (idxf >= 0.0f && idxf <= 255.0f) ? v : 0.0f;
    }
    float m = (xx * xx + yy * yy <= 16384.0f) ? 1.0f : 0.0f;
    int p = b * PIX + i * 256 + j;
    float upd = yprev[p] + stepp[0] * acc * m;
    ws[OFF_YUPD + p] = upd;
    dout[NPIX + p] = upd;          // second output
}

// ---------------- K4: conv1 (2 -> 32) + relu ----------------
__global__ void k_conv1(const float* __restrict__ yconc, const float* __restrict__ w1,
                        const float* __restrict__ b1, float* __restrict__ ws) {
    int p = blockIdx.x * 256 + threadIdx.x;
    int b = p >> 16, rem = p & 65535, y = rem >> 8, x = rem & 255;
    const float* __restrict__ in0 = ws + OFF_YUPD + b * PIX;
    const float* __restrict__ in1 = yconc + b * PIX;
    float acc[NCNN];
    #pragma unroll
    for (int oc = 0; oc < NCNN; ++oc) acc[oc] = b1[oc];
    #pragma unroll
    for (int ic = 0; ic < 2; ++ic) {
        const float* __restrict__ in = ic ? in1 : in0;
        float v[9];
        #pragma unroll
        for (int ky = 0; ky < 3; ++ky)
            #pragma unroll
            for (int kx = 0; kx < 3; ++kx) {
                int yy = y + ky - 1, xx = x + kx - 1;
                v[ky * 3 + kx] = ((unsigned)yy < 256u && (unsigned)xx < 256u) ? in[yy * 256 + xx] : 0.0f;
            }
        #pragma unroll
        for (int oc = 0; oc < NCNN; ++oc) {
            const float* wp = w1 + (oc * 2 + ic) * 9;
            #pragma unroll
            for (int t = 0; t < 9; ++t) acc[oc] += v[t] * wp[t];
        }
    }
    float* out = ws + OFF_H1 + b * (NCNN * PIX) + rem;
    #pragma unroll
    for (int oc = 0; oc < NCNN; ++oc) out[oc * PIX] = fmaxf(acc[oc], 0.0f);
}

// ---------------- K5: conv2 (32 -> 32) + relu ----------------
__global__ void k_conv2(const float* __restrict__ w2, const float* __restrict__ b2,
                        float* __restrict__ ws) {
    int p = blockIdx.x * 256 + threadIdx.x;
    int b = p >> 16, rem = p & 65535, y = rem >> 8, x = rem & 255;
    const float* __restrict__ base = ws + OFF_H1 + b * (NCNN * PIX);
    float acc[NCNN];
    #pragma unroll
    for (int oc = 0; oc < NCNN; ++oc) acc[oc] = b2[oc];
    for (int ic = 0; ic < NCNN; ++ic) {
        const float* __restrict__ in = base + ic * PIX;
        float v[9];
        #pragma unroll
        for (int ky = 0; ky < 3; ++ky)
            #pragma unroll
            for (int kx = 0; kx < 3; ++kx) {
                int yy = y + ky - 1, xx = x + kx - 1;
                v[ky * 3 + kx] = ((unsigned)yy < 256u && (unsigned)xx < 256u) ? in[yy * 256 + xx] : 0.0f;
            }
        #pragma unroll
        for (int oc = 0; oc < NCNN; ++oc) {
            const float* wp = w2 + (oc * NCNN + ic) * 9;
            #pragma unroll
            for (int t = 0; t < 9; ++t) acc[oc] += v[t] * wp[t];
        }
    }
    float* out = ws + OFF_H2 + b * (NCNN * PIX) + rem;
    #pragma unroll
    for (int oc = 0; oc < NCNN; ++oc) out[oc * PIX] = fmaxf(acc[oc], 0.0f);
}

// ---------------- K6: conv3 (32 -> 1) ----------------
__global__ void k_conv3(const float* __restrict__ w3, const float* __restrict__ b3,
                        const float* __restrict__ ws, float* __restrict__ dout) {
    int p = blockIdx.x * 256 + threadIdx.x;
    int b = p >> 16, rem = p & 65535, y = rem >> 8, x = rem & 255;
    const float* __restrict__ base = ws + OFF_H2 + b * (NCNN * PIX);
    float acc = b3[0];
    for (int ic = 0; ic < NCNN; ++ic) {
        const float* __restrict__ in = base + ic * PIX;
        const float* wp = w3 + ic * 9;
        #pragma unroll
        for (int ky = 0; ky < 3; ++ky)
            #pragma unroll
            for (int kx = 0; kx < 3; ++kx) {
                int yy = y + ky - 1, xx = x + kx - 1;
                float v = ((unsigned)yy < 256u && (unsigned)xx < 256u) ? in[yy * 256 + xx] : 0.0f;
                acc += v * wp[ky * 3 + kx];
            }
    }
    dout[p] = acc;    // first output
}

extern "C" void kernel_launch(void* const* d_in, const int* in_sizes, int n_in,
                              void* d_out, int out_size, void* d_ws, size_t ws_size,
                              hipStream_t stream) {
    const float* xsino  = (const float*)d_in[0];
    const float* yprev  = (const float*)d_in[1];
    const float* yconc  = (const float*)d_in[2];
    const float* angles = (const float*)d_in[3];
    const float* stepp  = (const float*)d_in[4];
    const float* w1 = (const float*)d_in[5];
    const float* b1 = (const float*)d_in[6];
    const float* w2 = (const float*)d_in[7];
    const float* b2 = (const float*)d_in[8];
    const float* w3 = (const float*)d_in[9];
    const float* b3 = (const float*)d_in[10];
    float* out = (float*)d_out;
    float* ws  = (float*)d_ws;

    k_precompute<<<1, 512, 0, stream>>>(angles, ws);
    k_mask_img<<<NPIX / 256, 256, 0, stream>>>(yprev, ws);
    k_radon_fwd<<<BATCH * NANG * 8, 256, 0, stream>>>(ws);
    k_filter<<<BATCH * NANG, 256, 0, stream>>>(xsino, ws);
    k_backproj<<<BATCH * IMGS, 256, 0, stream>>>(yprev, stepp, ws, out);
    k_conv1<<<NPIX / 256, 256, 0, stream>>>(yconc, w1, b1, ws);
    k_conv2<<<NPIX / 256, 256, 0, stream>>>(w2, b2, ws);
    k_conv3<<<NPIX / 256, 256, 0, stream>>>(w3, b3, ws, out);
}

// Round 3
// 215.416 us; speedup vs baseline: 1.6837x; 1.6837x over previous
//
#include <hip/hip_runtime.h>
#include <math.h>

// Problem constants
#define IMGS 256
#define NANG 50
#define BATCH 4
#define NCNN 32
#define PIX (IMGS*IMGS)              // 65536
#define NPIX (BATCH*PIX)             // 262144

// Padded channel-last tensors: [258][258][32] bf16 per batch
#define PROW 258
#define PPIX (PROW*PROW)             // 66564
#define PB   (PPIX*NCNN)             // 2130048 bf16 per batch

// Workspace layout (float offsets)
#define OFF_COS   0
#define OFF_SIN   64
#define OFF_TAPS  128        // 511 taps (+1 pad)
#define OFF_MIMG  640        // 262144  masked image
#define OFF_PART  262784     // 8*51200 partial forward sums
#define OFF_FILT  672384     // 51200   filtered sinogram
#define OFF_YUPD  723584     // 262144  y_img_update
#define OFF_W2BF  985728     // 9216 bf16 = 4608 floats ([tap][oc][ic])
#define OFF_H1P   990336     // 4*PB bf16 = 4260096 floats
#define OFF_H2P   5250432    // 4*PB bf16 = 4260096 floats
// total 9510528 floats ~= 38 MB

static constexpr double PI_D = 3.14159265358979323846;

typedef unsigned short u16;
typedef unsigned int   u32;
typedef __bf16 bfrag __attribute__((ext_vector_type(8)));
typedef float  ffrag __attribute__((ext_vector_type(4)));

__device__ __forceinline__ u16 f2bf(float f) {
    u32 u = __float_as_uint(f);
    u += 0x7fffu + ((u >> 16) & 1u);     // RNE
    return (u16)(u >> 16);
}

// ---------------- K0: trig + ramp-filter taps (closed form) ----------------
// filter_sinogram == circular conv (P=512) with g=irfft(ramp), ramp[k]=2k/512.
// g[n]*512 = (-1)^n + S(n)/128, S(n)=sum_{k=1}^{255} k cos(k*pi*n/256)
//          = (256cos(255t)-255cos(256t)-1)/(2(1-cos t)), t = pi*n/256.
__global__ void k_precompute(const float* __restrict__ angles, float* __restrict__ ws) {
    int tid = threadIdx.x;
    if (tid < NANG) {
        float a = angles[tid];
        ws[OFF_COS + tid] = cosf(a);
        ws[OFF_SIN + tid] = sinf(a);
    }
    if (tid < 511) {
        int d = tid - 255;
        int n = d < 0 ? -d : d;
        double g;
        if (n == 0) {
            g = 256.0 / 512.0;
        } else {
            double th = PI_D * (double)n / 256.0;
            double S = (256.0 * cos(255.0 * th) - 255.0 * cos(256.0 * th) - 1.0)
                       / (2.0 * (1.0 - cos(th)));
            double sign = (n & 1) ? -1.0 : 1.0;
            g = (sign + S / 128.0) / 512.0;
        }
        ws[OFF_TAPS + tid] = (float)(g * PI_D / 100.0);   // fold pi/(2A), A=50
    }
}

// ---------------- K0a: w2 -> bf16 [tap][oc][ic] ----------------
__global__ void k_wprep(const float* __restrict__ w2, float* __restrict__ ws) {
    int i = blockIdx.x * 256 + threadIdx.x;   // i = t*1024 + oc*32 + ic
    if (i >= 9216) return;
    int t = i >> 10, oc = (i >> 5) & 31, ic = i & 31;
    u16* w2bf = (u16*)(ws + OFF_W2BF);
    w2bf[i] = f2bf(w2[(oc * 32 + ic) * 9 + t]);
}

// ---------------- K0c: zero padded borders of h1p/h2p ----------------
__global__ void k_zero_borders(float* __restrict__ ws) {
    int idx = blockIdx.x * 256 + threadIdx.x;
    if (idx >= 2 * BATCH * 1028) return;
    int tensor = idx / (BATCH * 1028);
    int r = idx % (BATCH * 1028);
    int b = r / 1028, i = r % 1028;
    int y, x;
    if (i < 516) { y = (i < 258) ? 0 : 257; x = i % 258; }
    else         { int j = i - 516; y = 1 + (j >> 1); x = (j & 1) * 257; }
    u16* base = (u16*)(ws + (tensor ? OFF_H2P : OFF_H1P)) + b * PB + (y * PROW + x) * NCNN;
    uint4 z = make_uint4(0, 0, 0, 0);
    uint4* p4 = (uint4*)base;
    p4[0] = z; p4[1] = z; p4[2] = z; p4[3] = z;
}

// ---------------- K0b: mask image ----------------
__global__ void k_mask_img(const float* __restrict__ yprev, float* __restrict__ ws) {
    int p = blockIdx.x * 256 + threadIdx.x;
    int i = (p >> 8) & 255, j = p & 255;
    float di = (float)i - 127.5f, dj = (float)j - 127.5f;
    float m = (di * di + dj * dj <= 16384.0f) ? 1.0f : 0.0f;
    ws[OFF_MIMG + p] = yprev[p] * m;
}

__device__ __forceinline__ float ldpix(const float* __restrict__ im, int i, int j) {
    return ((unsigned)i < 256u && (unsigned)j < 256u) ? im[i * 256 + j] : 0.0f;
}

// ---------------- K1: forward radon, 8-way split over t ----------------
__global__ void k_radon_fwd(float* __restrict__ ws) {
    const float* __restrict__ mimg = ws + OFF_MIMG;
    int bi  = blockIdx.x;
    int seg = bi & 7;
    int ra  = bi >> 3;            // b*50 + a
    int a   = ra % NANG;
    int b   = ra / NANG;
    float cs = ws[OFF_COS + a], sn = ws[OFF_SIN + a];
    int s = threadIdx.x;
    float sc = (float)s - 127.5f;
    const float* __restrict__ im = mimg + b * PIX;
    float acc = 0.0f;
    int t0 = seg * 32;
    for (int t = t0; t < t0 + 32; ++t) {
        float tc  = (float)t - 127.5f;
        float col = (sc * cs - tc * sn) + 127.5f;
        float row = (sc * sn + tc * cs) + 127.5f;
        float fr = floorf(row), fc = floorf(col);
        int   i0 = (int)fr,     j0 = (int)fc;
        float wr = row - fr,    wc = col - fc;
        float v00 = ldpix(im, i0,     j0);
        float v01 = ldpix(im, i0,     j0 + 1);
        float v10 = ldpix(im, i0 + 1, j0);
        float v11 = ldpix(im, i0 + 1, j0 + 1);
        acc += v00 * (1.0f - wr) * (1.0f - wc) + v01 * (1.0f - wr) * wc
             + v10 * wr * (1.0f - wc)          + v11 * wr * wc;
    }
    ws[OFF_PART + (seg * 200 + ra) * 256 + s] = acc;
}

// ---------------- K2: reduce partials, subtract sino, 511-tap filter ----------------
__global__ void k_filter(const float* __restrict__ xsino, float* __restrict__ ws) {
    __shared__ float srow[256];
    __shared__ float staps[512];
    int r = blockIdx.x, tid = threadIdx.x;
    float v = -xsino[r * 256 + tid];
    #pragma unroll
    for (int seg = 0; seg < 8; ++seg) v += ws[OFF_PART + (seg * 200 + r) * 256 + tid];
    srow[tid] = v;
    staps[tid] = ws[OFF_TAPS + tid];
    if (tid < 255) staps[256 + tid] = ws[OFF_TAPS + 256 + tid];
    __syncthreads();
    float acc = 0.0f;
    #pragma unroll 8
    for (int m = 0; m < 256; ++m) acc += srow[m] * staps[tid - m + 255];
    ws[OFF_FILT + r * 256 + tid] = acc;
}

// ---------------- K3: backprojection + y_img_update ----------------
__global__ void k_backproj(const float* __restrict__ yprev, const float* __restrict__ stepp,
                           float* __restrict__ ws, float* __restrict__ dout) {
    __shared__ float sf[NANG * 256];
    __shared__ float scs[NANG], ssn[NANG];
    int b = blockIdx.x >> 8, i = blockIdx.x & 255, j = threadIdx.x;
    for (int idx = threadIdx.x; idx < NANG * 256; idx += 256)
        sf[idx] = ws[OFF_FILT + b * (NANG * 256) + idx];
    if (threadIdx.x < NANG) {
        scs[threadIdx.x] = ws[OFF_COS + threadIdx.x];
        ssn[threadIdx.x] = ws[OFF_SIN + threadIdx.x];
    }
    __syncthreads();
    float yy = (float)i - 127.5f, xx = (float)j - 127.5f;
    float acc = 0.0f;
    #pragma unroll 5
    for (int a = 0; a < NANG; ++a) {
        float idxf = xx * scs[a] + yy * ssn[a] + 127.5f;
        float fl = floorf(idxf);
        int i0 = (int)fl;
        i0 = min(max(i0, 0), 254);
        float w = idxf - (float)i0;
        float v = sf[a * 256 + i0] * (1.0f - w) + sf[a * 256 + i0 + 1] * w;
        acc += (idxf >= 0.0f && idxf <= 255.0f) ? v : 0.0f;
    }
    float m = (xx * xx + yy * yy <= 16384.0f) ? 1.0f : 0.0f;
    int p = b * PIX + i * 256 + j;
    float upd = yprev[p] + stepp[0] * acc * m;
    ws[OFF_YUPD + p] = upd;
    dout[NPIX + p] = upd;          // second output
}

// ---------------- K4: conv1 (2 -> 32) + relu -> padded ch-last bf16 ----------------
__global__ void k_conv1(const float* __restrict__ yconc, const float* __restrict__ w1,
                        const float* __restrict__ b1, float* __restrict__ ws) {
    int p = blockIdx.x * 256 + threadIdx.x;
    int b = p >> 16, rem = p & 65535, y = rem >> 8, x = rem & 255;
    const float* __restrict__ in0 = ws + OFF_YUPD + b * PIX;
    const float* __restrict__ in1 = yconc + b * PIX;
    float v[18];
    #pragma unroll
    for (int ic = 0; ic < 2; ++ic) {
        const float* __restrict__ in = ic ? in1 : in0;
        #pragma unroll
        for (int ky = 0; ky < 3; ++ky)
            #pragma unroll
            for (int kx = 0; kx < 3; ++kx) {
                int yy = y + ky - 1, xx = x + kx - 1;
                v[ic * 9 + ky * 3 + kx] =
                    ((unsigned)yy < 256u && (unsigned)xx < 256u) ? in[yy * 256 + xx] : 0.0f;
            }
    }
    u32 pk[16];
    #pragma unroll
    for (int oc2 = 0; oc2 < 16; ++oc2) {
        float a0 = b1[2 * oc2], a1 = b1[2 * oc2 + 1];
        const float* wp = w1 + (2 * oc2) * 18;
        #pragma unroll
        for (int t = 0; t < 18; ++t) { a0 += v[t] * wp[t]; a1 += v[t] * wp[18 + t]; }
        a0 = fmaxf(a0, 0.0f); a1 = fmaxf(a1, 0.0f);
        pk[oc2] = (u32)f2bf(a0) | ((u32)f2bf(a1) << 16);
    }
    u16* op = (u16*)(ws + OFF_H1P) + b * PB + ((y + 1) * PROW + (x + 1)) * NCNN;
    uint4* o4 = (uint4*)op;
    #pragma unroll
    for (int q = 0; q < 4; ++q)
        o4[q] = make_uint4(pk[4 * q], pk[4 * q + 1], pk[4 * q + 2], pk[4 * q + 3]);
}

// ---------------- K5: conv2 (32 -> 32) + relu, MFMA implicit GEMM ----------------
// Per tap: C[px][oc] += A[px][ic] * W_t[ic][oc]; 16x16x32 bf16 MFMA, fp32 acc.
__global__ __launch_bounds__(256) void k_conv2(const float* __restrict__ b2,
                                               float* __restrict__ ws) {
    const u16* __restrict__ w2bf = (const u16*)(ws + OFF_W2BF);
    const u16* __restrict__ h1p  = (const u16*)(ws + OFF_H1P);
    u16* __restrict__ h2p        = (u16*)(ws + OFF_H2P);
    int wg = blockIdx.x;                 // b*256 + y
    int b = wg >> 8, y = wg & 255;
    int wave = threadIdx.x >> 6;
    int lane = threadIdx.x & 63;
    int m = lane & 15, quad = lane >> 4; // m: A-row(px)/B-col(oc)/C-col(oc)
    const u16* __restrict__ h1b = h1p + b * PB;
    u16* __restrict__ h2b       = h2p + b * PB;

    // B fragments (weights), all 9 taps x 2 oc-tiles, held in registers
    bfrag Bf[9][2];
    #pragma unroll
    for (int t = 0; t < 9; ++t) {
        const u16* wp = w2bf + t * 1024 + m * 32 + quad * 8;
        Bf[t][0] = *(const bfrag*)(wp);
        Bf[t][1] = *(const bfrag*)(wp + 16 * 32);
    }
    float bias0 = b2[m], bias1 = b2[m + 16];

    #pragma unroll
    for (int it = 0; it < 4; ++it) {
        int xs = wave * 64 + it * 16;    // 16 output pixels per MFMA M-tile
        bfrag Af[9];
        #pragma unroll
        for (int t = 0; t < 9; ++t) {
            int ty = t / 3, tx = t % 3;
            const u16* ap = h1b + ((y + ty) * PROW + xs + m + tx) * NCNN + quad * 8;
            Af[t] = *(const bfrag*)ap;
        }
        ffrag c0 = {0.f, 0.f, 0.f, 0.f}, c1 = {0.f, 0.f, 0.f, 0.f};
        #pragma unroll
        for (int t = 0; t < 9; ++t) {
            c0 = __builtin_amdgcn_mfma_f32_16x16x32_bf16(Af[t], Bf[t][0], c0, 0, 0, 0);
            c1 = __builtin_amdgcn_mfma_f32_16x16x32_bf16(Af[t], Bf[t][1], c1, 0, 0, 0);
        }
        // C/D layout: col(oc)=lane&15, row(px)=quad*4+r
        #pragma unroll
        for (int r = 0; r < 4; ++r) {
            int px = xs + quad * 4 + r;
            u16* op = h2b + ((y + 1) * PROW + px + 1) * NCNN;
            op[m]      = f2bf(fmaxf(c0[r] + bias0, 0.0f));
            op[m + 16] = f2bf(fmaxf(c1[r] + bias1, 0.0f));
        }
    }
}

// ---------------- K6: conv3 (32 -> 1), bf16 ch-last reads ----------------
__global__ void k_conv3(const float* __restrict__ w3, const float* __restrict__ b3,
                        const float* __restrict__ ws, float* __restrict__ dout) {
    __shared__ float sw[288];            // sw[t*32+ic] = w3[ic*9+t]
    int tid = threadIdx.x;
    for (int idx = tid; idx < 288; idx += 256) {   // FIX: grid-stride fill (was if(tid<288) with 256 threads)
        int t = idx >> 5, ic = idx & 31;
        sw[idx] = w3[ic * 9 + t];
    }
    __syncthreads();
    int p = blockIdx.x * 256 + tid;
    int b = p >> 16, rem = p & 65535, y = rem >> 8, x = rem & 255;
    const u16* __restrict__ h2b = (const u16*)(ws + OFF_H2P) + b * PB;
    float acc = b3[0];
    #pragma unroll
    for (int t = 0; t < 9; ++t) {
        int ty = t / 3, tx = t % 3;
        const uint4* q = (const uint4*)(h2b + ((y + ty) * PROW + x + tx) * NCNN);
        #pragma unroll
        for (int qq = 0; qq < 4; ++qq) {
            uint4 w4 = q[qq];
            u32 wv[4] = {w4.x, w4.y, w4.z, w4.w};
            #pragma unroll
            for (int k = 0; k < 4; ++k) {
                int ch = qq * 8 + k * 2;
                float f0 = __uint_as_float(wv[k] << 16);
                float f1 = __uint_as_float(wv[k] & 0xffff0000u);
                acc += f0 * sw[t * 32 + ch] + f1 * sw[t * 32 + ch + 1];
            }
        }
    }
    dout[p] = acc;    // first output
}

extern "C" void kernel_launch(void* const* d_in, const int* in_sizes, int n_in,
                              void* d_out, int out_size, void* d_ws, size_t ws_size,
                              hipStream_t stream) {
    const float* xsino  = (const float*)d_in[0];
    const float* yprev  = (const float*)d_in[1];
    const float* yconc  = (const float*)d_in[2];
    const float* angles = (const float*)d_in[3];
    const float* stepp  = (const float*)d_in[4];
    const float* w1 = (const float*)d_in[5];
    const float* b1 = (const float*)d_in[6];
    const float* w2 = (const float*)d_in[7];
    const float* b2 = (const float*)d_in[8];
    const float* w3 = (const float*)d_in[9];
    const float* b3 = (const float*)d_in[10];
    float* out = (float*)d_out;
    float* ws  = (float*)d_ws;

    k_precompute<<<1, 512, 0, stream>>>(angles, ws);
    k_wprep<<<36, 256, 0, stream>>>(w2, ws);
    k_zero_borders<<<(2 * BATCH * 1028 + 255) / 256, 256, 0, stream>>>(ws);
    k_mask_img<<<NPIX / 256, 256, 0, stream>>>(yprev, ws);
    k_radon_fwd<<<BATCH * NANG * 8, 256, 0, stream>>>(ws);
    k_filter<<<BATCH * NANG, 256, 0, stream>>>(xsino, ws);
    k_backproj<<<BATCH * IMGS, 256, 0, stream>>>(yprev, stepp, ws, out);
    k_conv1<<<NPIX / 256, 256, 0, stream>>>(yconc, w1, b1, ws);
    k_conv2<<<BATCH * IMGS, 256, 0, stream>>>(b2, ws);
    k_conv3<<<NPIX / 256, 256, 0, stream>>>(w3, b3, ws, out);
}

// Round 4
// 198.124 us; speedup vs baseline: 1.8307x; 1.0873x over previous
//
#include <hip/hip_runtime.h>
#include <math.h>

// Problem constants
#define IMGS 256
#define NANG 50
#define BATCH 4
#define NCNN 32
#define PIX (IMGS*IMGS)              // 65536
#define NPIX (BATCH*PIX)             // 262144

// Padded channel-last tensors: [258][258][32] bf16 per batch
#define PROW 258
#define PPIX (PROW*PROW)             // 66564
#define PB   (PPIX*NCNN)             // 2130048 bf16 per batch

// Workspace layout (float offsets)
#define OFF_COS   0
#define OFF_SIN   64
#define OFF_TAPS  128        // 511 taps (+1 pad)
#define OFF_MIMG  640        // 262144 masked image [i][j]
#define OFF_MIMGT 262784     // 262144 masked image transposed [j][i]
#define OFF_PART  524928     // 8*51200 partial forward sums
#define OFF_FILT  934528     // 51200  filtered sinogram
#define OFF_YUPD  985728     // 262144 y_img_update
#define OFF_W2BF  1247872    // 9216 bf16 = 4608 floats ([tap][oc][ic])
#define OFF_H1P   1252480    // 4*PB bf16 = 4260096 floats
#define OFF_H2P   5512576    // 4*PB bf16 = 4260096 floats
// total 9772672 floats ~= 39 MB

static constexpr double PI_D = 3.14159265358979323846;

typedef unsigned short u16;
typedef unsigned int   u32;
typedef __bf16 bfrag __attribute__((ext_vector_type(8)));
typedef float  ffrag __attribute__((ext_vector_type(4)));

__device__ __forceinline__ u16 f2bf(float f) {
    u32 u = __float_as_uint(f);
    u += 0x7fffu + ((u >> 16) & 1u);     // RNE
    return (u16)(u >> 16);
}

// ---------------- K_setup: fused precompute (1096 blocks) ----------------
// blocks [0,1024): mask image -> mimg + mimgT
// blocks [1024,1060): w2 -> bf16 [tap][oc][ic]
// blocks [1060,1062): ramp taps (closed form)
// block  1062: trig
// blocks [1063,1096): zero padded borders of h1p/h2p
__global__ void k_setup(const float* __restrict__ angles, const float* __restrict__ yprev,
                        const float* __restrict__ w2, float* __restrict__ ws) {
    int gid = blockIdx.x, tid = threadIdx.x;
    if (gid < 1024) {
        int p = gid * 256 + tid;
        int b = p >> 16, i = (p >> 8) & 255, j = p & 255;
        float di = (float)i - 127.5f, dj = (float)j - 127.5f;
        float m = (di * di + dj * dj <= 16384.0f) ? 1.0f : 0.0f;
        float v = yprev[p] * m;
        ws[OFF_MIMG + p] = v;
        ws[OFF_MIMGT + b * PIX + j * 256 + i] = v;
    } else if (gid < 1060) {
        int i = (gid - 1024) * 256 + tid;   // i = t*1024 + oc*32 + ic
        if (i < 9216) {
            int t = i >> 10, oc = (i >> 5) & 31, ic = i & 31;
            ((u16*)(ws + OFF_W2BF))[i] = f2bf(w2[(oc * 32 + ic) * 9 + t]);
        }
    } else if (gid < 1062) {
        // filter_sinogram == circular conv (P=512) with g=irfft(ramp), ramp[k]=2k/512.
        // g[n]*512 = (-1)^n + S(n)/128, S(n)=sum_{k=1}^{255} k cos(k pi n/256)
        //          = (256cos(255t)-255cos(256t)-1)/(2(1-cos t)), t = pi n/256.
        int q = (gid - 1060) * 256 + tid;
        if (q < 511) {
            int d = q - 255;
            int n = d < 0 ? -d : d;
            double g;
            if (n == 0) {
                g = 0.5;
            } else {
                double th = PI_D * (double)n / 256.0;
                double S = (256.0 * cos(255.0 * th) - 255.0 * cos(256.0 * th) - 1.0)
                           / (2.0 * (1.0 - cos(th)));
                double sign = (n & 1) ? -1.0 : 1.0;
                g = (sign + S / 128.0) / 512.0;
            }
            ws[OFF_TAPS + q] = (float)(g * PI_D / 100.0);   // fold pi/(2A), A=50
        }
    } else if (gid == 1062) {
        if (tid < NANG) {
            float a = angles[tid];
            ws[OFF_COS + tid] = cosf(a);
            ws[OFF_SIN + tid] = sinf(a);
        }
    } else {
        int idx = (gid - 1063) * 256 + tid;
        if (idx < 2 * BATCH * 1028) {
            int tensor = idx / (BATCH * 1028);
            int r = idx % (BATCH * 1028);
            int b = r / 1028, i = r % 1028;
            int y, x;
            if (i < 516) { y = (i < 258) ? 0 : 257; x = i % 258; }
            else         { int j = i - 516; y = 1 + (j >> 1); x = (j & 1) * 257; }
            u16* base = (u16*)(ws + (tensor ? OFF_H2P : OFF_H1P)) + b * PB + (y * PROW + x) * NCNN;
            uint4 z = make_uint4(0, 0, 0, 0);
            uint4* p4 = (uint4*)base;
            p4[0] = z; p4[1] = z; p4[2] = z; p4[3] = z;
        }
    }
}

__device__ __forceinline__ float ldpix(const float* __restrict__ im, int i, int j) {
    return ((unsigned)i < 256u && (unsigned)j < 256u) ? im[i * 256 + j] : 0.0f;
}

// ---------------- K1: forward radon, 8-way t-split, layout-adaptive ----------------
// Sample addr row-coef wrt lane = min(|sin|,|cos|) via transposed image copy.
__global__ __launch_bounds__(256) void k_radon_fwd(float* __restrict__ ws) {
    int bi  = blockIdx.x;
    int seg = bi & 7;
    int ra  = bi >> 3;            // b*50 + a
    int a   = ra % NANG;
    int b   = ra / NANG;
    float cs = ws[OFF_COS + a], sn = ws[OFF_SIN + a];
    bool tr = fabsf(sn) > fabsf(cs);
    const float* __restrict__ im = ws + (tr ? OFF_MIMGT : OFF_MIMG) + b * PIX;
    // row = s*Ac + t*Bc + c ; col = s*Cc + t*Dc + c
    float Ac = tr ? cs : sn;
    float Bc = tr ? -sn : cs;
    float Cc = tr ? sn : cs;
    float Dc = tr ? cs : -sn;
    int s = threadIdx.x;
    float sc = (float)s - 127.5f;
    float rbase = sc * Ac + 127.5f;
    float cbase = sc * Cc + 127.5f;
    float acc = 0.0f;
    int t0 = seg * 32;
    for (int tt = 0; tt < 32; tt += 4) {
        float v[4][4], wr[4], wc[4];
        #pragma unroll
        for (int u = 0; u < 4; ++u) {
            float tc = (float)(t0 + tt + u) - 127.5f;
            float row = rbase + tc * Bc;
            float col = cbase + tc * Dc;
            float fr = floorf(row), fc = floorf(col);
            int i0 = (int)fr, j0 = (int)fc;
            wr[u] = row - fr; wc[u] = col - fc;
            v[u][0] = ldpix(im, i0,     j0);
            v[u][1] = ldpix(im, i0,     j0 + 1);
            v[u][2] = ldpix(im, i0 + 1, j0);
            v[u][3] = ldpix(im, i0 + 1, j0 + 1);
        }
        #pragma unroll
        for (int u = 0; u < 4; ++u) {
            float t_ = v[u][0] + (v[u][1] - v[u][0]) * wc[u];
            float bq = v[u][2] + (v[u][3] - v[u][2]) * wc[u];
            acc += t_ + (bq - t_) * wr[u];
        }
    }
    ws[OFF_PART + (seg * 200 + ra) * 256 + s] = acc;
}

// ---------------- K2: reduce partials, subtract sino, 511-tap filter ----------------
__global__ void k_filter(const float* __restrict__ xsino, float* __restrict__ ws) {
    __shared__ float srow[256];
    __shared__ float staps[512];
    int r = blockIdx.x, tid = threadIdx.x;
    float v = -xsino[r * 256 + tid];
    #pragma unroll
    for (int seg = 0; seg < 8; ++seg) v += ws[OFF_PART + (seg * 200 + r) * 256 + tid];
    srow[tid] = v;
    staps[tid] = ws[OFF_TAPS + tid];
    if (tid < 255) staps[256 + tid] = ws[OFF_TAPS + 256 + tid];
    __syncthreads();
    float acc = 0.0f;
    #pragma unroll 8
    for (int m = 0; m < 256; ++m) acc += srow[m] * staps[tid - m + 255];
    ws[OFF_FILT + r * 256 + tid] = acc;
}

// ---------------- K3: backprojection + y_img_update ----------------
__global__ void k_backproj(const float* __restrict__ yprev, const float* __restrict__ stepp,
                           float* __restrict__ ws, float* __restrict__ dout) {
    __shared__ float sf[NANG * 256];
    __shared__ float scs[NANG], ssn[NANG];
    int b = blockIdx.x >> 8, i = blockIdx.x & 255, j = threadIdx.x;
    for (int idx = threadIdx.x; idx < NANG * 256; idx += 256)
        sf[idx] = ws[OFF_FILT + b * (NANG * 256) + idx];
    if (threadIdx.x < NANG) {
        scs[threadIdx.x] = ws[OFF_COS + threadIdx.x];
        ssn[threadIdx.x] = ws[OFF_SIN + threadIdx.x];
    }
    __syncthreads();
    float yy = (float)i - 127.5f, xx = (float)j - 127.5f;
    float acc = 0.0f;
    #pragma unroll 5
    for (int a = 0; a < NANG; ++a) {
        float idxf = xx * scs[a] + yy * ssn[a] + 127.5f;
        float fl = floorf(idxf);
        int i0 = (int)fl;
        i0 = min(max(i0, 0), 254);
        float w = idxf - (float)i0;
        float v = sf[a * 256 + i0] * (1.0f - w) + sf[a * 256 + i0 + 1] * w;
        acc += (idxf >= 0.0f && idxf <= 255.0f) ? v : 0.0f;
    }
    float m = (xx * xx + yy * yy <= 16384.0f) ? 1.0f : 0.0f;
    int p = b * PIX + i * 256 + j;
    float upd = yprev[p] + stepp[0] * acc * m;
    ws[OFF_YUPD + p] = upd;
    dout[NPIX + p] = upd;          // second output
}

// ---------------- K4: conv1 (2 -> 32) + relu -> padded ch-last bf16 ----------------
__global__ void k_conv1(const float* __restrict__ yconc, const float* __restrict__ w1,
                        const float* __restrict__ b1, float* __restrict__ ws) {
    int p = blockIdx.x * 256 + threadIdx.x;
    int b = p >> 16, rem = p & 65535, y = rem >> 8, x = rem & 255;
    const float* __restrict__ in0 = ws + OFF_YUPD + b * PIX;
    const float* __restrict__ in1 = yconc + b * PIX;
    float v[18];
    #pragma unroll
    for (int ic = 0; ic < 2; ++ic) {
        const float* __restrict__ in = ic ? in1 : in0;
        #pragma unroll
        for (int ky = 0; ky < 3; ++ky)
            #pragma unroll
            for (int kx = 0; kx < 3; ++kx) {
                int yy = y + ky - 1, xx = x + kx - 1;
                v[ic * 9 + ky * 3 + kx] =
                    ((unsigned)yy < 256u && (unsigned)xx < 256u) ? in[yy * 256 + xx] : 0.0f;
            }
    }
    u32 pk[16];
    #pragma unroll
    for (int oc2 = 0; oc2 < 16; ++oc2) {
        float a0 = b1[2 * oc2], a1 = b1[2 * oc2 + 1];
        const float* wp = w1 + (2 * oc2) * 18;
        #pragma unroll
        for (int t = 0; t < 18; ++t) { a0 += v[t] * wp[t]; a1 += v[t] * wp[18 + t]; }
        a0 = fmaxf(a0, 0.0f); a1 = fmaxf(a1, 0.0f);
        pk[oc2] = (u32)f2bf(a0) | ((u32)f2bf(a1) << 16);
    }
    u16* op = (u16*)(ws + OFF_H1P) + b * PB + ((y + 1) * PROW + (x + 1)) * NCNN;
    uint4* o4 = (uint4*)op;
    #pragma unroll
    for (int q = 0; q < 4; ++q)
        o4[q] = make_uint4(pk[4 * q], pk[4 * q + 1], pk[4 * q + 2], pk[4 * q + 3]);
}

// ---------------- K5: conv2 (32 -> 32) + relu, MFMA implicit GEMM ----------------
__global__ __launch_bounds__(256) void k_conv2(const float* __restrict__ b2,
                                               float* __restrict__ ws) {
    const u16* __restrict__ w2bf = (const u16*)(ws + OFF_W2BF);
    const u16* __restrict__ h1p  = (const u16*)(ws + OFF_H1P);
    u16* __restrict__ h2p        = (u16*)(ws + OFF_H2P);
    int wg = blockIdx.x;                 // b*256 + y
    int b = wg >> 8, y = wg & 255;
    int wave = threadIdx.x >> 6;
    int lane = threadIdx.x & 63;
    int m = lane & 15, quad = lane >> 4;
    const u16* __restrict__ h1b = h1p + b * PB;
    u16* __restrict__ h2b       = h2p + b * PB;

    bfrag Bf[9][2];
    #pragma unroll
    for (int t = 0; t < 9; ++t) {
        const u16* wp = w2bf + t * 1024 + m * 32 + quad * 8;
        Bf[t][0] = *(const bfrag*)(wp);
        Bf[t][1] = *(const bfrag*)(wp + 16 * 32);
    }
    float bias0 = b2[m], bias1 = b2[m + 16];

    #pragma unroll
    for (int it = 0; it < 4; ++it) {
        int xs = wave * 64 + it * 16;
        bfrag Af[9];
        #pragma unroll
        for (int t = 0; t < 9; ++t) {
            int ty = t / 3, tx = t % 3;
            const u16* ap = h1b + ((y + ty) * PROW + xs + m + tx) * NCNN + quad * 8;
            Af[t] = *(const bfrag*)ap;
        }
        ffrag c0 = {0.f, 0.f, 0.f, 0.f}, c1 = {0.f, 0.f, 0.f, 0.f};
        #pragma unroll
        for (int t = 0; t < 9; ++t) {
            c0 = __builtin_amdgcn_mfma_f32_16x16x32_bf16(Af[t], Bf[t][0], c0, 0, 0, 0);
            c1 = __builtin_amdgcn_mfma_f32_16x16x32_bf16(Af[t], Bf[t][1], c1, 0, 0, 0);
        }
        #pragma unroll
        for (int r = 0; r < 4; ++r) {
            int px = xs + quad * 4 + r;
            u16* op = h2b + ((y + 1) * PROW + px + 1) * NCNN;
            op[m]      = f2bf(fmaxf(c0[r] + bias0, 0.0f));
            op[m + 16] = f2bf(fmaxf(c1[r] + bias1, 0.0f));
        }
    }
}

// ---------------- K6: conv3 (32 -> 1), bf16 ch-last reads ----------------
__global__ void k_conv3(const float* __restrict__ w3, const float* __restrict__ b3,
                        const float* __restrict__ ws, float* __restrict__ dout) {
    __shared__ float sw[288];            // sw[t*32+ic] = w3[ic*9+t]
    int tid = threadIdx.x;
    for (int idx = tid; idx < 288; idx += 256) {
        int t = idx >> 5, ic = idx & 31;
        sw[idx] = w3[ic * 9 + t];
    }
    __syncthreads();
    int p = blockIdx.x * 256 + tid;
    int b = p >> 16, rem = p & 65535, y = rem >> 8, x = rem & 255;
    const u16* __restrict__ h2b = (const u16*)(ws + OFF_H2P) + b * PB;
    float acc = b3[0];
    #pragma unroll
    for (int t = 0; t < 9; ++t) {
        int ty = t / 3, tx = t % 3;
        const uint4* q = (const uint4*)(h2b + ((y + ty) * PROW + x + tx) * NCNN);
        #pragma unroll
        for (int qq = 0; qq < 4; ++qq) {
            uint4 w4 = q[qq];
            u32 wv[4] = {w4.x, w4.y, w4.z, w4.w};
            #pragma unroll
            for (int k = 0; k < 4; ++k) {
                int ch = qq * 8 + k * 2;
                float f0 = __uint_as_float(wv[k] << 16);
                float f1 = __uint_as_float(wv[k] & 0xffff0000u);
                acc += f0 * sw[t * 32 + ch] + f1 * sw[t * 32 + ch + 1];
            }
        }
    }
    dout[p] = acc;    // first output
}

extern "C" void kernel_launch(void* const* d_in, const int* in_sizes, int n_in,
                              void* d_out, int out_size, void* d_ws, size_t ws_size,
                              hipStream_t stream) {
    const float* xsino  = (const float*)d_in[0];
    const float* yprev  = (const float*)d_in[1];
    const float* yconc  = (const float*)d_in[2];
    const float* angles = (const float*)d_in[3];
    const float* stepp  = (const float*)d_in[4];
    const float* w1 = (const float*)d_in[5];
    const float* b1 = (const float*)d_in[6];
    const float* w2 = (const float*)d_in[7];
    const float* b2 = (const float*)d_in[8];
    const float* w3 = (const float*)d_in[9];
    const float* b3 = (const float*)d_in[10];
    float* out = (float*)d_out;
    float* ws  = (float*)d_ws;

    k_setup<<<1096, 256, 0, stream>>>(angles, yprev, w2, ws);
    k_radon_fwd<<<BATCH * NANG * 8, 256, 0, stream>>>(ws);
    k_filter<<<BATCH * NANG, 256, 0, stream>>>(xsino, ws);
    k_backproj<<<BATCH * IMGS, 256, 0, stream>>>(yprev, stepp, ws, out);
    k_conv1<<<NPIX / 256, 256, 0, stream>>>(yconc, w1, b1, ws);
    k_conv2<<<BATCH * IMGS, 256, 0, stream>>>(b2, ws);
    k_conv3<<<NPIX / 256, 256, 0, stream>>>(w3, b3, ws, out);
}

// Round 5
// 170.644 us; speedup vs baseline: 2.1255x; 1.1610x over previous
//
#include <hip/hip_runtime.h>
#include <math.h>

// Problem constants
#define IMGS 256
#define NANG 50
#define BATCH 4
#define NCNN 32
#define PIX (IMGS*IMGS)              // 65536
#define NPIX (BATCH*PIX)             // 262144

// Padded channel-last tensors: [258][258][32] bf16 per batch
#define PROW 258
#define PPIX (PROW*PROW)             // 66564
#define PB   (PPIX*NCNN)             // 2130048 bf16 per batch

// Workspace layout (float offsets)
#define OFF_COS   0
#define OFF_SIN   64
#define OFF_TAPS  128        // 511 taps (+1 pad)
#define OFF_PART  640        // 51200 raw sinogram Ay (b,a,s)
#define OFF_FILT  51840      // 51200 filtered sinogram
#define OFF_YUPD  103040     // 262144 y_img_update
#define OFF_W2BF  365184     // 9216 bf16 = 4608 floats ([tap][oc][ic])
#define OFF_H1P   369792     // 4*PB bf16 = 4260096 floats
#define OFF_H2P   4629888    // 4*PB bf16 = 4260096 floats

static constexpr double PI_D = 3.14159265358979323846;

typedef unsigned short u16;
typedef unsigned int   u32;
typedef unsigned long long u64;
typedef __bf16 bfrag __attribute__((ext_vector_type(8)));
typedef float  ffrag __attribute__((ext_vector_type(4)));

__device__ __forceinline__ u16 f2bf(float f) {
    u32 u = __float_as_uint(f);
    u += 0x7fffu + ((u >> 16) & 1u);     // RNE
    return (u16)(u >> 16);
}

// ---------------- K_setup: fused precompute (72 blocks) ----------------
// [0,36): w2 -> bf16 [tap][oc][ic] ; [36,38): ramp taps ; 38: trig ;
// [39,72): zero padded borders of h1p/h2p
__global__ void k_setup(const float* __restrict__ angles,
                        const float* __restrict__ w2, float* __restrict__ ws) {
    int gid = blockIdx.x, tid = threadIdx.x;
    if (gid < 36) {
        int i = gid * 256 + tid;   // i = t*1024 + oc*32 + ic
        if (i < 9216) {
            int t = i >> 10, oc = (i >> 5) & 31, ic = i & 31;
            ((u16*)(ws + OFF_W2BF))[i] = f2bf(w2[(oc * 32 + ic) * 9 + t]);
        }
    } else if (gid < 38) {
        // filter_sinogram == circular conv (P=512) with g=irfft(ramp), ramp[k]=2k/512.
        // g[n]*512 = (-1)^n + S(n)/128, S(n)=sum k cos(k pi n/256)
        //          = (256cos(255t)-255cos(256t)-1)/(2(1-cos t)), t = pi n/256.
        int q = (gid - 36) * 256 + tid;
        if (q < 511) {
            int d = q - 255;
            int n = d < 0 ? -d : d;
            double g;
            if (n == 0) {
                g = 0.5;
            } else {
                double th = PI_D * (double)n / 256.0;
                double S = (256.0 * cos(255.0 * th) - 255.0 * cos(256.0 * th) - 1.0)
                           / (2.0 * (1.0 - cos(th)));
                double sign = (n & 1) ? -1.0 : 1.0;
                g = (sign + S / 128.0) / 512.0;
            }
            ws[OFF_TAPS + q] = (float)(g * PI_D / 100.0);   // fold pi/(2A), A=50
        }
    } else if (gid == 38) {
        if (tid < NANG) {
            float a = angles[tid];
            ws[OFF_COS + tid] = cosf(a);
            ws[OFF_SIN + tid] = sinf(a);
        }
    } else {
        int idx = (gid - 39) * 256 + tid;
        if (idx < 2 * BATCH * 1028) {
            int tensor = idx / (BATCH * 1028);
            int r = idx % (BATCH * 1028);
            int b = r / 1028, i = r % 1028;
            int y, x;
            if (i < 516) { y = (i < 258) ? 0 : 257; x = i % 258; }
            else         { int j = i - 516; y = 1 + (j >> 1); x = (j & 1) * 257; }
            u16* base = (u16*)(ws + (tensor ? OFF_H2P : OFF_H1P)) + b * PB + (y * PROW + x) * NCNN;
            uint4 z = make_uint4(0, 0, 0, 0);
            uint4* p4 = (uint4*)base;
            p4[0] = z; p4[1] = z; p4[2] = z; p4[3] = z;
        }
    }
}

// ---------------- K1: forward radon, LDS-staged bf16 image ----------------
// One block per (b,a). Image stored bf16, rows 0..257 (img row i -> stored i+1),
// cols stored at +2 (img col j -> stored j+2), pitch 262 u16 = 131 dwords.
// 131 odd => row stride walks all 32 banks (<=2-way conflicts, free).
// Bilinear sample = 4 LDS dword reads (col pair in-dword, row pair at +131).
#define RPITCH_D 131            // dwords per LDS row
__global__ __launch_bounds__(512) void k_radon_fwd(const float* __restrict__ yprev,
                                                   float* __restrict__ ws) {
    __shared__ u16 limg[258 * 262];      // 135,192 B
    __shared__ float spart[512];
    u32* l32 = (u32*)limg;
    int ra = blockIdx.x;                 // b*50 + a
    int a = ra % NANG, b = ra / NANG;
    int tid = threadIdx.x;

    // zero borders: dwords 0 & 129 of all 258 rows; dwords 1..128 of rows 0,257
    for (int z = tid; z < 772; z += 512) {
        int addr;
        if (z < 258)      addr = z * RPITCH_D;                    // col pair 0,1
        else if (z < 516) addr = (z - 258) * RPITCH_D + 129;      // col pair 258,259
        else if (z < 644) addr = (z - 516) + 1;                   // row 0
        else              addr = 257 * RPITCH_D + (z - 644) + 1;  // row 257
        l32[addr] = 0;
    }
    // stage interior: mask inline, fp32 -> bf16
    const float* __restrict__ src = yprev + b * PIX;
    for (int idx = tid; idx < 16384; idx += 512) {
        int r = idx >> 6, c4 = (idx & 63) << 2;
        float4 v = *(const float4*)(src + r * 256 + c4);
        float di = (float)r - 127.5f;
        float rr = di * di;
        float d0 = (float)c4 - 127.5f;
        v.x = (rr + d0 * d0 <= 16384.0f) ? v.x : 0.0f;
        v.y = (rr + (d0 + 1.0f) * (d0 + 1.0f) <= 16384.0f) ? v.y : 0.0f;
        v.z = (rr + (d0 + 2.0f) * (d0 + 2.0f) <= 16384.0f) ? v.z : 0.0f;
        v.w = (rr + (d0 + 3.0f) * (d0 + 3.0f) <= 16384.0f) ? v.w : 0.0f;
        u32 p0 = (u32)f2bf(v.x) | ((u32)f2bf(v.y) << 16);
        u32 p1 = (u32)f2bf(v.z) | ((u32)f2bf(v.w) << 16);
        int dw = (r + 1) * RPITCH_D + (c4 >> 1) + 1;
        l32[dw] = p0; l32[dw + 1] = p1;
    }
    __syncthreads();

    float cs = ws[OFF_COS + a], sn = ws[OFF_SIN + a];
    int s = tid & 255, half = tid >> 8;
    float sc = (float)s - 127.5f;
    // row = s*sn + t*cs + c ; col = s*cs - t*sn + c
    float t0c = 128.0f * (float)half - 127.5f;
    float rowv = sc * sn + t0c * cs + 127.5f;
    float colv = sc * cs - t0c * sn + 127.5f;
    float acc = 0.0f;
    #pragma unroll 4
    for (int it = 0; it < 128; ++it) {
        float fr = floorf(rowv), fc = floorf(colv);
        float wr = rowv - fr, wc = colv - fc;
        int i0 = (int)fr, j0 = (int)fc;
        bool valid = (rowv > -1.0f) & (rowv < 256.0f) & (colv > -1.0f) & (colv < 256.0f);
        int i0c = min(max(i0, -1), 255);
        int j0c = min(max(j0, -1), 255);
        int ca = j0c + 2;
        int ka = ca >> 1;
        int sh = (ca & 1) << 4;
        int dw = (i0c + 1) * RPITCH_D + ka;
        u32 A = l32[dw],            C = l32[dw + 1];
        u32 B = l32[dw + RPITCH_D], D = l32[dw + RPITCH_D + 1];
        u32 top = (u32)((((u64)C << 32) | (u64)A) >> sh);
        u32 bot = (u32)((((u64)D << 32) | (u64)B) >> sh);
        float tl = __uint_as_float(top << 16);
        float tr_ = __uint_as_float(top & 0xffff0000u);
        float bl = __uint_as_float(bot << 16);
        float br = __uint_as_float(bot & 0xffff0000u);
        float tv = tl + (tr_ - tl) * wc;
        float bv = bl + (br - bl) * wc;
        float sv = tv + (bv - tv) * wr;
        acc += valid ? sv : 0.0f;
        rowv += cs; colv -= sn;
    }
    spart[tid] = acc;
    __syncthreads();
    if (tid < 256)
        ws[OFF_PART + ra * 256 + tid] = spart[tid] + spart[tid + 256];
}

// ---------------- K2: subtract sino, 511-tap ramp filter ----------------
__global__ void k_filter(const float* __restrict__ xsino, float* __restrict__ ws) {
    __shared__ float srow[256];
    __shared__ float staps[512];
    int r = blockIdx.x, tid = threadIdx.x;
    srow[tid] = ws[OFF_PART + r * 256 + tid] - xsino[r * 256 + tid];
    staps[tid] = ws[OFF_TAPS + tid];
    if (tid < 255) staps[256 + tid] = ws[OFF_TAPS + 256 + tid];
    __syncthreads();
    float acc = 0.0f;
    #pragma unroll 8
    for (int m = 0; m < 256; ++m) acc += srow[m] * staps[tid - m + 255];
    ws[OFF_FILT + r * 256 + tid] = acc;
}

// ---------------- K3: backprojection + y_img_update ----------------
__global__ void k_backproj(const float* __restrict__ yprev, const float* __restrict__ stepp,
                           float* __restrict__ ws, float* __restrict__ dout) {
    __shared__ float sf[NANG * 256];
    __shared__ float scs[NANG], ssn[NANG];
    int b = blockIdx.x >> 8, i = blockIdx.x & 255, j = threadIdx.x;
    for (int idx = threadIdx.x; idx < NANG * 256; idx += 256)
        sf[idx] = ws[OFF_FILT + b * (NANG * 256) + idx];
    if (threadIdx.x < NANG) {
        scs[threadIdx.x] = ws[OFF_COS + threadIdx.x];
        ssn[threadIdx.x] = ws[OFF_SIN + threadIdx.x];
    }
    __syncthreads();
    float yy = (float)i - 127.5f, xx = (float)j - 127.5f;
    float acc = 0.0f;
    #pragma unroll 5
    for (int a = 0; a < NANG; ++a) {
        float idxf = xx * scs[a] + yy * ssn[a] + 127.5f;
        float fl = floorf(idxf);
        int i0 = (int)fl;
        i0 = min(max(i0, 0), 254);
        float w = idxf - (float)i0;
        float v = sf[a * 256 + i0] * (1.0f - w) + sf[a * 256 + i0 + 1] * w;
        acc += (idxf >= 0.0f && idxf <= 255.0f) ? v : 0.0f;
    }
    float m = (xx * xx + yy * yy <= 16384.0f) ? 1.0f : 0.0f;
    int p = b * PIX + i * 256 + j;
    float upd = yprev[p] + stepp[0] * acc * m;
    ws[OFF_YUPD + p] = upd;
    dout[NPIX + p] = upd;          // second output
}

// ---------------- K4: conv1 (2 -> 32) + relu -> padded ch-last bf16 ----------------
__global__ void k_conv1(const float* __restrict__ yconc, const float* __restrict__ w1,
                        const float* __restrict__ b1, float* __restrict__ ws) {
    int p = blockIdx.x * 256 + threadIdx.x;
    int b = p >> 16, rem = p & 65535, y = rem >> 8, x = rem & 255;
    const float* __restrict__ in0 = ws + OFF_YUPD + b * PIX;
    const float* __restrict__ in1 = yconc + b * PIX;
    float v[18];
    #pragma unroll
    for (int ic = 0; ic < 2; ++ic) {
        const float* __restrict__ in = ic ? in1 : in0;
        #pragma unroll
        for (int ky = 0; ky < 3; ++ky)
            #pragma unroll
            for (int kx = 0; kx < 3; ++kx) {
                int yy = y + ky - 1, xx = x + kx - 1;
                v[ic * 9 + ky * 3 + kx] =
                    ((unsigned)yy < 256u && (unsigned)xx < 256u) ? in[yy * 256 + xx] : 0.0f;
            }
    }
    u32 pk[16];
    #pragma unroll
    for (int oc2 = 0; oc2 < 16; ++oc2) {
        float a0 = b1[2 * oc2], a1 = b1[2 * oc2 + 1];
        const float* wp = w1 + (2 * oc2) * 18;
        #pragma unroll
        for (int t = 0; t < 18; ++t) { a0 += v[t] * wp[t]; a1 += v[t] * wp[18 + t]; }
        a0 = fmaxf(a0, 0.0f); a1 = fmaxf(a1, 0.0f);
        pk[oc2] = (u32)f2bf(a0) | ((u32)f2bf(a1) << 16);
    }
    u16* op = (u16*)(ws + OFF_H1P) + b * PB + ((y + 1) * PROW + (x + 1)) * NCNN;
    uint4* o4 = (uint4*)op;
    #pragma unroll
    for (int q = 0; q < 4; ++q)
        o4[q] = make_uint4(pk[4 * q], pk[4 * q + 1], pk[4 * q + 2], pk[4 * q + 3]);
}

// ---------------- K5: conv2 (32 -> 32) + relu, MFMA implicit GEMM ----------------
__global__ __launch_bounds__(256) void k_conv2(const float* __restrict__ b2,
                                               float* __restrict__ ws) {
    const u16* __restrict__ w2bf = (const u16*)(ws + OFF_W2BF);
    const u16* __restrict__ h1p  = (const u16*)(ws + OFF_H1P);
    u16* __restrict__ h2p        = (u16*)(ws + OFF_H2P);
    int wg = blockIdx.x;                 // b*256 + y
    int b = wg >> 8, y = wg & 255;
    int wave = threadIdx.x >> 6;
    int lane = threadIdx.x & 63;
    int m = lane & 15, quad = lane >> 4;
    const u16* __restrict__ h1b = h1p + b * PB;
    u16* __restrict__ h2b       = h2p + b * PB;

    bfrag Bf[9][2];
    #pragma unroll
    for (int t = 0; t < 9; ++t) {
        const u16* wp = w2bf + t * 1024 + m * 32 + quad * 8;
        Bf[t][0] = *(const bfrag*)(wp);
        Bf[t][1] = *(const bfrag*)(wp + 16 * 32);
    }
    float bias0 = b2[m], bias1 = b2[m + 16];

    #pragma unroll
    for (int it = 0; it < 4; ++it) {
        int xs = wave * 64 + it * 16;
        bfrag Af[9];
        #pragma unroll
        for (int t = 0; t < 9; ++t) {
            int ty = t / 3, tx = t % 3;
            const u16* ap = h1b + ((y + ty) * PROW + xs + m + tx) * NCNN + quad * 8;
            Af[t] = *(const bfrag*)ap;
        }
        ffrag c0 = {0.f, 0.f, 0.f, 0.f}, c1 = {0.f, 0.f, 0.f, 0.f};
        #pragma unroll
        for (int t = 0; t < 9; ++t) {
            c0 = __builtin_amdgcn_mfma_f32_16x16x32_bf16(Af[t], Bf[t][0], c0, 0, 0, 0);
            c1 = __builtin_amdgcn_mfma_f32_16x16x32_bf16(Af[t], Bf[t][1], c1, 0, 0, 0);
        }
        #pragma unroll
        for (int r = 0; r < 4; ++r) {
            int px = xs + quad * 4 + r;
            u16* op = h2b + ((y + 1) * PROW + px + 1) * NCNN;
            op[m]      = f2bf(fmaxf(c0[r] + bias0, 0.0f));
            op[m + 16] = f2bf(fmaxf(c1[r] + bias1, 0.0f));
        }
    }
}

// ---------------- K6: conv3 (32 -> 1), bf16 ch-last reads ----------------
__global__ void k_conv3(const float* __restrict__ w3, const float* __restrict__ b3,
                        const float* __restrict__ ws, float* __restrict__ dout) {
    __shared__ float sw[288];            // sw[t*32+ic] = w3[ic*9+t]
    int tid = threadIdx.x;
    for (int idx = tid; idx < 288; idx += 256) {
        int t = idx >> 5, ic = idx & 31;
        sw[idx] = w3[ic * 9 + t];
    }
    __syncthreads();
    int p = blockIdx.x * 256 + tid;
    int b = p >> 16, rem = p & 65535, y = rem >> 8, x = rem & 255;
    const u16* __restrict__ h2b = (const u16*)(ws + OFF_H2P) + b * PB;
    float acc = b3[0];
    #pragma unroll
    for (int t = 0; t < 9; ++t) {
        int ty = t / 3, tx = t % 3;
        const uint4* q = (const uint4*)(h2b + ((y + ty) * PROW + x + tx) * NCNN);
        #pragma unroll
        for (int qq = 0; qq < 4; ++qq) {
            uint4 w4 = q[qq];
            u32 wv[4] = {w4.x, w4.y, w4.z, w4.w};
            #pragma unroll
            for (int k = 0; k < 4; ++k) {
                int ch = qq * 8 + k * 2;
                float f0 = __uint_as_float(wv[k] << 16);
                float f1 = __uint_as_float(wv[k] & 0xffff0000u);
                acc += f0 * sw[t * 32 + ch] + f1 * sw[t * 32 + ch + 1];
            }
        }
    }
    dout[p] = acc;    // first output
}

extern "C" void kernel_launch(void* const* d_in, const int* in_sizes, int n_in,
                              void* d_out, int out_size, void* d_ws, size_t ws_size,
                              hipStream_t stream) {
    const float* xsino  = (const float*)d_in[0];
    const float* yprev  = (const float*)d_in[1];
    const float* yconc  = (const float*)d_in[2];
    const float* angles = (const float*)d_in[3];
    const float* stepp  = (const float*)d_in[4];
    const float* w1 = (const float*)d_in[5];
    const float* b1 = (const float*)d_in[6];
    const float* w2 = (const float*)d_in[7];
    const float* b2 = (const float*)d_in[8];
    const float* w3 = (const float*)d_in[9];
    const float* b3 = (const float*)d_in[10];
    float* out = (float*)d_out;
    float* ws  = (float*)d_ws;

    k_setup<<<72, 256, 0, stream>>>(angles, w2, ws);
    k_radon_fwd<<<BATCH * NANG, 512, 0, stream>>>(yprev, ws);
    k_filter<<<BATCH * NANG, 256, 0, stream>>>(xsino, ws);
    k_backproj<<<BATCH * IMGS, 256, 0, stream>>>(yprev, stepp, ws, out);
    k_conv1<<<NPIX / 256, 256, 0, stream>>>(yconc, w1, b1, ws);
    k_conv2<<<BATCH * IMGS, 256, 0, stream>>>(b2, ws);
    k_conv3<<<NPIX / 256, 256, 0, stream>>>(w3, b3, ws, out);
}